// Round 8
// baseline (254.078 us; speedup 1.0000x reference)
//
#include <hip/hip_runtime.h>
#include <hip/hip_bf16.h>

typedef short short8 __attribute__((ext_vector_type(8)));
typedef float f32x4 __attribute__((ext_vector_type(4)));
typedef unsigned short u16;

#define SCALE_C 0.17677669529663687f

__device__ __forceinline__ u16 f2b(float f) {
  union { float f; unsigned int u; } v; v.f = f;
  unsigned int u = v.u;
  return (u16)((u + 0x7FFFu + ((u >> 16) & 1u)) >> 16);
}
__device__ __forceinline__ float b2f(u16 b) {
  union { unsigned int u; float f; } v; v.u = ((unsigned int)b) << 16; return v.f;
}
__device__ __forceinline__ void glds16(const void* g, void* l) {
  __builtin_amdgcn_global_load_lds(
      (const __attribute__((address_space(1))) unsigned int*)g,
      (__attribute__((address_space(3))) unsigned int*)l, 16, 0, 0);
}

// ---------------- fp32 -> bf16 convert (both tensors, one kernel) ----------------
__global__ __launch_bounds__(256) void cvt2(const float* __restrict__ xq,
                                            const float* __restrict__ xkv,
                                            u16* __restrict__ yq, u16* __restrict__ ykv) {
  int b = blockIdx.x;
  const float* x; u16* y;
  if (b < 8192) { x = xq; y = yq; } else { x = xkv; y = ykv; b -= 8192; }
  size_t i = ((size_t)b * 256 + threadIdx.x) * 8;
  f32x4 a = *(const f32x4*)(x + i);
  f32x4 c = *(const f32x4*)(x + i + 4);
  short8 o; u16* op = (u16*)&o;
#pragma unroll
  for (int e = 0; e < 4; ++e) { op[e] = f2b(a[e]); op[4 + e] = f2b(c[e]); }
  *(short8*)(y + i) = o;
}

// ---------------- prep kernels ----------------
__global__ void prep0(const float* Wq, const float* Wk, const float* Wv, const float* Wo,
                      const float* bk, const float* bv,
                      u16* wqT, u16* wkvT, u16* woT, float* bkv) {
  int j = blockIdx.x, t = threadIdx.x;
  wqT[j * 256 + t] = f2b(Wq[t * 256 + j]);
  wkvT[j * 256 + t] = f2b(Wk[t * 256 + j]);
  wkvT[(256 + j) * 256 + t] = f2b(Wv[t * 256 + j]);
  woT[j * 256 + t] = f2b(Wo[t * 256 + j]);
  if (t == 0) { bkv[j] = bk[j]; bkv[256 + j] = bv[j]; }
}

__global__ void prep1(const float* Wt, const float* Wo, const float* bt, const float* bo,
                      float* wtloT, float* btlo) {
  __shared__ float woj[256];
  int j = blockIdx.x, c = threadIdx.x;
  woj[c] = Wo[c * 256 + j];
  __syncthreads();
  float s = 0.f;
  const float* wr = Wt + c * 256;
#pragma unroll 8
  for (int t = 0; t < 256; ++t) s += wr[t] * woj[t];
  wtloT[j * 256 + c] = s;  // = Wtlo[c][j]
  if (c == 0) {
    float b = bo[j];
    for (int t = 0; t < 256; ++t) b += bt[t] * woj[t];
    btlo[j] = b;
  }
}

__global__ void prep2(const float* pk, const float* wtloT, const u16* woT, u16* B5) {
  int n = blockIdx.x >> 8, j = blockIdx.x & 255, t = threadIdx.x;
  u16* r = B5 + ((size_t)(n * 256 + j)) * 512;
  r[t] = f2b(pk[n * 256 + t] * wtloT[j * 256 + t]);
  r[256 + t] = woT[j * 256 + t];
}

// ---------------- GEMM: round-3 proven skeleton, glds-only staging ----------------
// 128x128 tile, 4 waves (2x2), BK=64, 2-barrier loop, 32KB LDS.
// LDS rows of 64 bf16 (128B, 8 granules of 16B); XOR g^(row&7) applied via
// pre-swizzled GLOBAL source (glds dest linear), reads swizzled (rule #21).
// MODE 0: fused G1+G2 (KT=4, bf16 C via swizzled LDS restage -> 16B/lane stores).
// MODE 1: G3 dual-A (KT=8, v then q), per-n B5, fp32 direct out.
template <int MODE>
__global__ __launch_bounds__(256) void gemm8(
    const u16* Xq, const u16* Xkv, const u16* wqT, const u16* wkvT,
    const float* bq, const float* bkv, u16* q_ws, u16* k_ws, u16* v_ws,
    const u16* B5, const float* btlo, float* outf) {
  __shared__ __align__(16) u16 sm[128 * 128];  // As = sm[0:8192], Bs = sm[8192:]
  u16* As = sm;
  u16* Bs = sm + 8192;
  constexpr int KT = (MODE == 0) ? 4 : 8;
  const int nwg = (MODE == 0) ? 3072 : 1024;
  int bid = blockIdx.x;
  int logical = (bid & 7) * (nwg >> 3) + (bid >> 3);  // XCD-chunked (nwg%8==0)
  int m0, n0, ldb;
  const u16 *Ab0, *Ab1, *Bb;
  const float* bias;
  u16* outb = nullptr;
  if constexpr (MODE == 0) {
    if (logical < 1024) {  // G1: q = x_q @ Wq
      m0 = (logical >> 1) * 128; n0 = (logical & 1) * 128;
      Ab0 = Xq; Bb = wqT; bias = bq; outb = q_ws;
    } else {               // G2: [k|v] = x_kv @ [Wk|Wv]
      int sub = logical - 1024;
      m0 = (sub >> 2) * 128; n0 = (sub & 3) * 128;
      Ab0 = Xkv; Bb = wkvT; bias = bkv; outb = (n0 & 256) ? v_ws : k_ws;
    }
    ldb = 256; Ab1 = Ab0;
  } else {
    m0 = (logical >> 1) * 128; n0 = (logical & 1) * 128;
    Ab0 = v_ws; Ab1 = q_ws; ldb = 512; bias = btlo;
    Bb = B5 + (size_t)(m0 >> 12) * 131072;
  }
  const u16* Bp = Bb + (size_t)n0 * ldb;
  int tid = threadIdx.x, lane = tid & 63, w = tid >> 6;
  int wm = w >> 1, wn = w & 1, rla = lane & 15, hi = lane >> 4;
  int grow = w * 8 + (lane >> 3);       // staging row 0..31 per 32-row group
  int gsg = (lane & 7) ^ (grow & 7);    // inverse-swizzled source granule

  f32x4 acc[4][4];
#pragma unroll
  for (int i = 0; i < 4; ++i)
#pragma unroll
    for (int j = 0; j < 4; ++j) acc[i][j] = (f32x4){0.f, 0.f, 0.f, 0.f};

  for (int kt = 0; kt < KT; ++kt) {
    const u16* Ak = (MODE == 1 && kt >= 4) ? Ab1 : Ab0;
    int koff = (MODE == 1) ? ((kt & 3) * 64) : (kt * 64);
#pragma unroll
    for (int p = 0; p < 4; ++p) {
      int r = p * 32 + grow;
      glds16(Ak + (size_t)(m0 + r) * 256 + koff + gsg * 8,
             &As[r * 64 + (lane & 7) * 8]);
      glds16(Bp + (size_t)r * ldb + kt * 64 + gsg * 8,
             &Bs[r * 64 + (lane & 7) * 8]);
    }
    __syncthreads();  // compiler drains vmcnt before barrier
#pragma unroll
    for (int kk = 0; kk < 2; ++kk) {
      short8 af[4], bf[4];
#pragma unroll
      for (int i = 0; i < 4; ++i) {
        int ra = wm * 64 + i * 16 + rla;
        int rb = wn * 64 + i * 16 + rla;
        int gd = kk * 4 + hi;
        af[i] = *(const short8*)&As[ra * 64 + ((gd ^ (ra & 7)) << 3)];
        bf[i] = *(const short8*)&Bs[rb * 64 + ((gd ^ (rb & 7)) << 3)];
      }
#pragma unroll
      for (int i = 0; i < 4; ++i)
#pragma unroll
        for (int j = 0; j < 4; ++j)
          acc[i][j] = __builtin_amdgcn_mfma_f32_16x16x32_bf16(af[i], bf[j], acc[i][j], 0, 0, 0);
    }
    __syncthreads();
  }

  // ---- epilogue ----
  if constexpr (MODE == 1) {
#pragma unroll
    for (int i = 0; i < 4; ++i)
#pragma unroll
      for (int j = 0; j < 4; ++j) {
        int cg = n0 + wn * 64 + j * 16 + rla;
        float bb = bias[cg];
#pragma unroll
        for (int e = 0; e < 4; ++e) {
          int row = m0 + wm * 64 + i * 16 + hi * 4 + e;
          outf[(size_t)row * 256 + cg] = acc[i][j][e] + bb;
        }
      }
  } else {
    // stage C (128x128 bf16, swizzled 256B rows) in sm, then full-line stores
#pragma unroll
    for (int i = 0; i < 4; ++i)
#pragma unroll
      for (int j = 0; j < 4; ++j) {
        int c = wn * 64 + j * 16 + rla;
        float bb = bias[n0 + c];
        int g = c >> 3;
#pragma unroll
        for (int e = 0; e < 4; ++e) {
          int r = wm * 64 + i * 16 + hi * 4 + e;
          int lg = (g & 8) | ((g & 7) ^ (r & 7));
          *(u16*)((char*)sm + r * 256 + lg * 16 + (c & 7) * 2) = f2b(acc[i][j][e] + bb);
        }
      }
    __syncthreads();
    int r = tid >> 1, hf = tid & 1;
    int nc = n0 & 255;
#pragma unroll
    for (int i = 0; i < 8; ++i) {
      int g2 = hf * 8 + i;
      int lg = (g2 & 8) | ((g2 & 7) ^ (r & 7));
      short8 vv = *(const short8*)((char*)sm + r * 256 + lg * 16);
      *(short8*)(outb + (size_t)(m0 + r) * 256 + nc + g2 * 8) = vv;
    }
  }
}

// ---------------- score: s[n][h][l] = ((act ⊙ g) @ Wa + ba) * SCALE ----------------
template <bool GATE>
__global__ __launch_bounds__(256) void score_k(const u16* act, const float* gate,
                                               const float* Wa, const float* ba, float* sout) {
  __shared__ float Ws[256][8];
  __shared__ float gs[256];
  int tid = threadIdx.x;
  for (int i = tid; i < 2048; i += 256) ((float*)Ws)[i] = Wa[i];
  if (GATE) gs[tid] = gate[(blockIdx.x >> 5) * 256 + tid];
  __syncthreads();
  int wv = tid >> 6, lane = tid & 63;
  int rl = lane >> 2, qq = lane & 3;
  for (int r0 = wv * 16; r0 < 128; r0 += 64) {
    int row = blockIdx.x * 128 + r0 + rl;
    const u16* ap = act + (size_t)row * 256 + qq * 64;
    float acc[8] = {0, 0, 0, 0, 0, 0, 0, 0};
#pragma unroll
    for (int ch = 0; ch < 8; ++ch) {
      short8 v = *(const short8*)(ap + ch * 8);
#pragma unroll
      for (int e = 0; e < 8; ++e) {
        int c = qq * 64 + ch * 8 + e;
        float x = b2f(((u16*)&v)[e]);
        if (GATE) x *= gs[c];
#pragma unroll
        for (int h = 0; h < 8; ++h) acc[h] += x * Ws[c][h];
      }
    }
#pragma unroll
    for (int h = 0; h < 8; ++h) {
      acc[h] += __shfl_xor(acc[h], 1);
      acc[h] += __shfl_xor(acc[h], 2);
    }
    if (qq == 0) {
      int n = row >> 12, l = row & 4095;
#pragma unroll
      for (int h = 0; h < 8; ++h)
        sout[(((size_t)n * 8 + h) << 12) + l] = (acc[h] + ba[h]) * SCALE_C;
    }
  }
}

// ---------------- pooled softmax, phase A: per (n,h,half-of-L) partials ----------
__global__ __launch_bounds__(256) void pool_a(const float* score, const u16* act,
                                              float* pmax, float* psum, float* pacc) {
  __shared__ float p[2048];
  __shared__ float red[8];
  __shared__ float wsum[4][32];
  int nh = blockIdx.x >> 1, half = blockIdx.x & 1;
  int n = nh >> 3, h = nh & 7;
  const float* s = score + ((size_t)nh << 12) + (half << 11);
  int tid = threadIdx.x;
  float v[8];
  float lmax = -3.0e38f;
#pragma unroll
  for (int i = 0; i < 8; ++i) { v[i] = s[i * 256 + tid]; lmax = fmaxf(lmax, v[i]); }
  for (int o = 32; o; o >>= 1) lmax = fmaxf(lmax, __shfl_xor(lmax, o));
  if ((tid & 63) == 0) red[tid >> 6] = lmax;
  __syncthreads();
  float m = fmaxf(fmaxf(red[0], red[1]), fmaxf(red[2], red[3]));
  float ls = 0.f;
#pragma unroll
  for (int i = 0; i < 8; ++i) { float e = __expf(v[i] - m); p[i * 256 + tid] = e; ls += e; }
  for (int o = 32; o; o >>= 1) ls += __shfl_xor(ls, o);
  if ((tid & 63) == 0) red[4 + (tid >> 6)] = ls;
  __syncthreads();
  float S = red[4] + red[5] + red[6] + red[7];
  float acc[32];
#pragma unroll
  for (int d = 0; d < 32; ++d) acc[d] = 0.f;
  const u16* ap = act + ((size_t)(n * 4096 + half * 2048)) * 256 + h * 32;
  for (int it = 0; it < 8; ++it) {
    int row = it * 256 + tid;
    float wgt = p[row];
    const u16* rp = ap + (size_t)row * 256;
#pragma unroll
    for (int ch = 0; ch < 4; ++ch) {
      short8 x = *(const short8*)(rp + ch * 8);
#pragma unroll
      for (int e = 0; e < 8; ++e) acc[ch * 8 + e] += wgt * b2f(((u16*)&x)[e]);
    }
  }
#pragma unroll
  for (int d = 0; d < 32; ++d)
    for (int o = 32; o; o >>= 1) acc[d] += __shfl_xor(acc[d], o);
  __syncthreads();
  if ((tid & 63) == 0)
#pragma unroll
    for (int d = 0; d < 32; ++d) wsum[tid >> 6][d] = acc[d];
  __syncthreads();
  if (tid < 32)
    pacc[(size_t)blockIdx.x * 32 + tid] =
        wsum[0][tid] + wsum[1][tid] + wsum[2][tid] + wsum[3][tid];
  if (tid == 0) { pmax[blockIdx.x] = m; psum[blockIdx.x] = S; }
}

// ---------------- pooled softmax, phase B: combine halves ----------------
__global__ void pool_b(const float* pmax, const float* psum, const float* pacc,
                       float* pooled) {
  int nh = blockIdx.x * 2 + (threadIdx.x >> 5);
  int d = threadIdx.x & 31;
  float m0 = pmax[nh * 2], m1 = pmax[nh * 2 + 1];
  float m = fmaxf(m0, m1);
  float w0 = __expf(m0 - m), w1 = __expf(m1 - m);
  float S = psum[nh * 2] * w0 + psum[nh * 2 + 1] * w1;
  float a = pacc[(size_t)(nh * 2) * 32 + d] * w0 + pacc[(size_t)(nh * 2 + 1) * 32 + d] * w1;
  int n = nh >> 3, h = nh & 7;
  pooled[(n << 8) + h * 32 + d] = a / S;
}

// ---------------- launch ----------------
extern "C" void kernel_launch(void* const* d_in, const int* in_sizes, int n_in,
                              void* d_out, int out_size, void* d_ws, size_t ws_size,
                              hipStream_t stream) {
  const float* x_q = (const float*)d_in[0];
  const float* x_kv = (const float*)d_in[1];
  const float* Wq = (const float*)d_in[2];
  const float* bq = (const float*)d_in[3];
  const float* Wqa = (const float*)d_in[4];
  const float* bqa = (const float*)d_in[5];
  const float* Wk = (const float*)d_in[6];
  const float* bk = (const float*)d_in[7];
  const float* Wka = (const float*)d_in[8];
  const float* bka = (const float*)d_in[9];
  const float* Wv = (const float*)d_in[10];
  const float* bv = (const float*)d_in[11];
  const float* Wt = (const float*)d_in[12];
  const float* bt = (const float*)d_in[13];
  const float* Wo = (const float*)d_in[14];
  const float* bo = (const float*)d_in[15];

  char* w = (char*)d_ws;
  size_t off = 0;
  u16* q_ws = (u16*)(w + off); off += (size_t)65536 * 256 * 2;   // 32MB
  u16* k_ws = (u16*)(w + off); off += (size_t)65536 * 256 * 2;   // 32MB
  u16* v_ws = (u16*)(w + off); off += (size_t)65536 * 256 * 2;   // 32MB
  float* score = (float*)(w + off); off += (size_t)16 * 8 * 4096 * 4;  // 2MB shared q/k
  float* pq = (float*)(w + off); off += 16 * 256 * 4;
  float* pk = (float*)(w + off); off += 16 * 256 * 4;
  float* pmax = (float*)(w + off); off += 256 * 4;
  float* psum = (float*)(w + off); off += 256 * 4;
  float* pacc = (float*)(w + off); off += 256 * 32 * 4;
  u16* wqT = (u16*)(w + off); off += 256 * 256 * 2;
  u16* wkvT = (u16*)(w + off); off += 512 * 256 * 2;
  u16* woT = (u16*)(w + off); off += 256 * 256 * 2;
  float* wtloT = (float*)(w + off); off += 256 * 256 * 4;
  float* btlo = (float*)(w + off); off += 256 * 4;
  float* bkv = (float*)(w + off); off += 512 * 4;
  u16* B5 = (u16*)(w + off); off += (size_t)16 * 256 * 512 * 2;  // 4MB
  if (ws_size < off) return;

  // bf16 X scratch inside the 64MB fp32 output buffer (proven in r3; G3 overwrites)
  u16* Xq = (u16*)d_out;
  u16* Xkv = Xq + (size_t)16777216;

  prep0<<<256, 256, 0, stream>>>(Wq, Wk, Wv, Wo, bk, bv, wqT, wkvT, woT, bkv);
  prep1<<<256, 256, 0, stream>>>(Wt, Wo, bt, bo, wtloT, btlo);
  cvt2<<<16384, 256, 0, stream>>>(x_q, x_kv, Xq, Xkv);

  // fused G1+G2
  gemm8<0><<<3072, 256, 0, stream>>>(Xq, Xkv, wqT, wkvT, bq, bkv,
                                     q_ws, k_ws, v_ws, nullptr, nullptr, nullptr);

  score_k<false><<<512, 256, 0, stream>>>(q_ws, nullptr, Wqa, bqa, score);
  pool_a<<<256, 256, 0, stream>>>(score, q_ws, pmax, psum, pacc);
  pool_b<<<64, 64, 0, stream>>>(pmax, psum, pacc, pq);

  score_k<true><<<512, 256, 0, stream>>>(k_ws, pq, Wka, bka, score);
  pool_a<<<256, 256, 0, stream>>>(score, k_ws, pmax, psum, pacc);
  pool_b<<<64, 64, 0, stream>>>(pmax, psum, pacc, pk);

  // per-n B5 = [diag(pk)*Wtlo ; Wo]  ([n][j][512])
  prep2<<<16 * 256, 256, 0, stream>>>(pk, wtloT, woT, B5);

  // G3: out = v @ B5_lo + q @ Wo + btlo  (dual-A bf16, K=512, fp32 out)
  gemm8<1><<<1024, 256, 0, stream>>>(nullptr, nullptr, nullptr, nullptr, nullptr, nullptr,
                                     q_ws, k_ws, v_ws, B5, btlo, (float*)d_out);
}